// Round 5
// baseline (553.508 us; speedup 1.0000x reference)
//
#include <hip/hip_runtime.h>
#include <hip/hip_bf16.h>

#define TWO_PI 6.28318530717958647692f

typedef __attribute__((ext_vector_type(8))) short bf16x8;
typedef __attribute__((ext_vector_type(4))) float f32x4;

__device__ __forceinline__ unsigned short f2bf(float v) {
    __hip_bfloat16 h = __float2bfloat16(v);
    return *(unsigned short*)&h;
}

__device__ __forceinline__ bf16x8 cvt8(float4 a, float4 b) {
    bf16x8 r;
    r[0] = (short)f2bf(a.x); r[1] = (short)f2bf(a.y);
    r[2] = (short)f2bf(a.z); r[3] = (short)f2bf(a.w);
    r[4] = (short)f2bf(b.x); r[5] = (short)f2bf(b.y);
    r[6] = (short)f2bf(b.z); r[7] = (short)f2bf(b.w);
    return r;
}

// Problem: B=32, M=N=128, I=O=64, NM=16.
// Spectral path keeps only km in {0..15, 112..127} (p=0..31) and kn=0..15 (q).
// T (the spectral contribution pre-irfft-along-v) has magnitude ~2e-5, so bf16
// for T and the cos/sin assembly matrix injects ~1e-8 on y — free.
//
// ws layout (float offsets):
//   w0t     @ 0        : 262144   (32 p x 64 i x 64 j complex)
//   w1t     @ 262144   : 262144   (2 h x 16 kv x 64 j x 64 o complex)
//   T       @ 524288   : 8388608  ([b][u][q][o] complex)
//   A       @ 8912896  : 8388608  ([b][m][kv][i] complex)  (dead after k2)
//   xft     @ 17301504 : 2097152  (dead after k3a)
//   c1      @ 19398656 : 2097152  (dead after k3b)
//   oft     @ 21495808 : 2097152  (dead after k4)
//   w1bt    @ 23592960 : 16384 u16  W1t[2][o:128][k:64] bf16
//   w2bt    @ 23601152 : 16384 u16  W2t[2][o:64][k:128] bf16
//   wlt_pre @ 23609344 : 4096 u16   w_lin^T [o:64][k:64] bf16, chunk-XOR-swizzled
//   ctb_pre @ 23611392 : 4096 u16   irfft coeff [v:128][k:32] bf16, swizzled

__global__ __launch_bounds__(256) void k0_prep(const float* __restrict__ ws0,
                                               const float* __restrict__ ws1,
                                               float2* __restrict__ w0t,
                                               float2* __restrict__ w1t)
{
    int tgt = blockIdx.x * 256 + threadIdx.x;   // 0..262143
    if (tgt < 131072) {
        int p = tgt >> 12;
        int rem = tgt & 4095;
        int i = rem >> 6, j = rem & 63;
        const float* s = (p < 16) ? ws0 : ws1;   // f=0 plane
        int px = p & 15;
        int base = ((i * 64 + j) * 16 + px) * 2;
        w0t[tgt] = make_float2(s[base], s[base + 1]);
    } else {
        int u = tgt - 131072;
        int h = u >> 16;
        int kv = (u >> 12) & 15;
        int j = (u >> 6) & 63;
        int o = u & 63;
        const float* s = (h ? ws1 : ws0) + 131072;  // f=1 plane
        int base = ((j * 64 + o) * 16 + kv) * 2;
        w1t[u] = make_float2(s[base], s[base + 1]);
    }
}

// head weights bf16-transposed + w_lin^T + irfft coefficient matrix
__global__ __launch_bounds__(256) void k0b_prep(const float* __restrict__ wb1,
                                                const float* __restrict__ wf1,
                                                const float* __restrict__ wb2,
                                                const float* __restrict__ wf2,
                                                const float* __restrict__ wl,
                                                unsigned short* __restrict__ w1bt,
                                                unsigned short* __restrict__ w2bt,
                                                unsigned short* __restrict__ wlt_pre,
                                                unsigned short* __restrict__ ctb_pre)
{
    int tgt = blockIdx.x * 256 + threadIdx.x;   // 0..40959
    if (tgt < 16384) {
        int head = tgt >> 13;
        int o = (tgt >> 6) & 127;
        int i = tgt & 63;
        const float* src = head ? wf1 : wb1;    // [64][128]
        w1bt[tgt] = f2bf(src[i * 128 + o]);
    } else if (tgt < 32768) {
        int u = tgt - 16384;
        int head = u >> 13;
        int o = (u >> 7) & 63;
        int c = u & 127;
        const float* src = head ? wf2 : wb2;    // [128][64]
        w2bt[u] = f2bf(src[c * 64 + o]);
    } else if (tgt < 36864) {
        int u = tgt - 32768;                    // 0..4095
        int o = u >> 6, i = u & 63;
        int chunk = (i >> 3) ^ (o & 7);
        wlt_pre[o * 64 + chunk * 8 + (i & 7)] = f2bf(wl[i * 64 + o]);
    } else {
        int u = tgt - 36864;                    // 0..4095
        int v = u >> 5, k = u & 31;             // v 0..127, k 0..31
        float val;
        if (k < 16) {
            val = (k == 0) ? (1.0f / 128.0f)
                           : (2.0f / 128.0f) * cosf(TWO_PI * k * v * (1.0f / 128.0f));
        } else {
            int q = k - 16;
            val = (q == 0) ? 0.f
                           : -(2.0f / 128.0f) * sinf(TWO_PI * q * v * (1.0f / 128.0f));
        }
        int chunk = (k >> 3) ^ ((v >> 1) & 3);
        ctb_pre[v * 32 + chunk * 8 + (k & 7)] = f2bf(val);
    }
}

// k1: A[b,m,kv,i] = sum_n x[b,m,n,i] * exp(-2pi i kv n/128), kv=0..15
__global__ __launch_bounds__(256) void k1_dft_n(const float* __restrict__ x,
                                                float2* __restrict__ A)
{
    __shared__ float Xs[128][64];
    __shared__ __align__(8) float2 tcs[128];
    const int t = threadIdx.x;
    const int bm = blockIdx.x;
    if (t < 128) { float a = t * (TWO_PI / 128.0f); tcs[t] = make_float2(cosf(a), sinf(a)); }
    const float4* xg4 = (const float4*)(x + (size_t)bm * 8192);
    float4* Xs4 = (float4*)&Xs[0][0];
    for (int k = t; k < 2048; k += 256) Xs4[k] = xg4[k];
    __syncthreads();
    const int i = t & 63;
    const int kv0 = (t >> 6) << 2;
    float re[4] = {0.f, 0.f, 0.f, 0.f}, im[4] = {0.f, 0.f, 0.f, 0.f};
    for (int n = 0; n < 128; ++n) {
        float v = Xs[n][i];
        #pragma unroll
        for (int j = 0; j < 4; ++j) {
            int idx = ((kv0 + j) * n) & 127;
            float2 w = tcs[idx];
            re[j] += v * w.x;
            im[j] -= v * w.y;
        }
    }
    float2* Ap = A + (size_t)bm * 1024;
    #pragma unroll
    for (int j = 0; j < 4; ++j) Ap[(kv0 + j) * 64 + i] = make_float2(re[j], im[j]);
}

// k2: xft[b,p,kv,i] = (1/128) sum_m A[b,m,kv,i] * exp(-2pi i km(p) m/128)
__global__ __launch_bounds__(256) void k2_dft_m(const float2* __restrict__ A,
                                                float2* __restrict__ xft)
{
    __shared__ float2 As[128][64];
    __shared__ __align__(8) float2 tcs[128];
    const int t = threadIdx.x;
    const int b = blockIdx.x >> 4, kv = blockIdx.x & 15;
    if (t < 128) { float a = t * (TWO_PI / 128.0f); tcs[t] = make_float2(cosf(a), sinf(a)); }
    for (int k = t; k < 8192; k += 256) {
        int m = k >> 6, i = k & 63;
        As[m][i] = A[((size_t)(b * 128 + m) * 16 + kv) * 64 + i];
    }
    __syncthreads();
    const int i = t & 63;
    const int p0 = (t >> 6) << 3;
    float2 acc[8];
    #pragma unroll
    for (int j = 0; j < 8; ++j) acc[j] = make_float2(0.f, 0.f);
    for (int m = 0; m < 128; ++m) {
        float2 a = As[m][i];
        #pragma unroll
        for (int j = 0; j < 8; ++j) {
            int p = p0 + j;
            int km = (p < 16) ? p : (96 + p);     // p>=16 -> km = 112 + (p-16)
            int idx = (km * m) & 127;
            float2 cs = tcs[idx];
            acc[j].x += a.x * cs.x + a.y * cs.y;  // a * e^{-i th}
            acc[j].y += a.y * cs.x - a.x * cs.y;
        }
    }
    const float sc = 1.0f / 128.0f;
    #pragma unroll
    for (int j = 0; j < 8; ++j)
        xft[((size_t)(b * 32 + p0 + j) * 16 + kv) * 64 + i] =
            make_float2(acc[j].x * sc, acc[j].y * sc);
}

// k3a: c1[b,p,kv,j] = sum_i xft[b,p,kv,i] * w0c[i,j,p]
__global__ __launch_bounds__(256) void k3a_spec1(const float2* __restrict__ xft,
                                                 const float2* __restrict__ w0t,
                                                 float2* __restrict__ c1)
{
    __shared__ __align__(16) float2 xs[16][64];
    __shared__ __align__(16) float2 w0s[64][64];
    const int t = threadIdx.x;
    const int b = blockIdx.x >> 5, p = blockIdx.x & 31;
    const float2* xg = xft + (size_t)(b * 32 + p) * 1024;
    for (int k = t; k < 1024; k += 256) ((float2*)xs)[k] = xg[k];
    const float4* wg = (const float4*)(w0t + (size_t)p * 4096);
    for (int k = t; k < 2048; k += 256) ((float4*)w0s)[k] = wg[k];
    __syncthreads();
    const int j = t & 63;
    const int kv0 = (t >> 6) << 2;
    float2 acc[4];
    #pragma unroll
    for (int q = 0; q < 4; ++q) acc[q] = make_float2(0.f, 0.f);
    for (int i = 0; i < 64; ++i) {
        float2 w = w0s[i][j];
        #pragma unroll
        for (int q = 0; q < 4; ++q) {
            float2 a = xs[kv0 + q][i];
            acc[q].x += a.x * w.x - a.y * w.y;
            acc[q].y += a.x * w.y + a.y * w.x;
        }
    }
    #pragma unroll
    for (int q = 0; q < 4; ++q)
        c1[((size_t)(b * 32 + p) * 16 + kv0 + q) * 64 + j] = acc[q];
}

// k3b: oft[b,p,kv,o] = sum_j c1[b,p,kv,j] * w1c[j,o,kv]  (weights per half h=p/16)
__global__ __launch_bounds__(256) void k3b_spec2(const float2* __restrict__ c1,
                                                 const float2* __restrict__ w1t,
                                                 float2* __restrict__ oft)
{
    __shared__ __align__(16) float2 cs[16][64];
    __shared__ __align__(16) float2 w1s[64][64];
    const int t = threadIdx.x;
    int id = blockIdx.x;
    const int h = id & 1; id >>= 1;
    const int kv = id & 15; const int b = id >> 4;
    for (int k = t; k < 1024; k += 256) {
        int pp = k >> 6, j = k & 63;
        cs[pp][j] = c1[((size_t)(b * 32 + h * 16 + pp) * 16 + kv) * 64 + j];
    }
    const float4* wg = (const float4*)(w1t + (size_t)(h * 16 + kv) * 4096);
    for (int k = t; k < 2048; k += 256) ((float4*)w1s)[k] = wg[k];
    __syncthreads();
    const int o = t & 63;
    const int pp0 = (t >> 6) << 2;
    float2 acc[4];
    #pragma unroll
    for (int q = 0; q < 4; ++q) acc[q] = make_float2(0.f, 0.f);
    for (int j = 0; j < 64; ++j) {
        float2 w = w1s[j][o];
        #pragma unroll
        for (int q = 0; q < 4; ++q) {
            float2 a = cs[pp0 + q][j];
            acc[q].x += a.x * w.x - a.y * w.y;
            acc[q].y += a.x * w.y + a.y * w.x;
        }
    }
    #pragma unroll
    for (int q = 0; q < 4; ++q)
        oft[((size_t)(b * 32 + h * 16 + pp0 + q) * 16 + kv) * 64 + o] = acc[q];
}

// k4: T[b,u,q,o] = sum_p oft[b,p,q,o] * exp(+2pi i km(p) u/128)
__global__ __launch_bounds__(256) void k4_idft_m(const float2* __restrict__ oft,
                                                 float2* __restrict__ T)
{
    __shared__ float2 Os[32][64];
    __shared__ __align__(8) float2 tcs[128];
    const int t = threadIdx.x;
    const int b = blockIdx.x >> 4, q = blockIdx.x & 15;
    if (t < 128) { float a = t * (TWO_PI / 128.0f); tcs[t] = make_float2(cosf(a), sinf(a)); }
    for (int k = t; k < 2048; k += 256) {
        int p = k >> 6, o = k & 63;
        Os[p][o] = oft[((size_t)(b * 32 + p) * 16 + q) * 64 + o];
    }
    __syncthreads();
    const int o = t & 63;
    const int u0 = (t >> 6) << 5;
    float2 op[32];
    #pragma unroll
    for (int p = 0; p < 32; ++p) op[p] = Os[p][o];
    for (int du = 0; du < 32; ++du) {
        int u = u0 + du;
        float ax = 0.f, ay = 0.f;
        #pragma unroll
        for (int p = 0; p < 32; ++p) {
            int km = (p < 16) ? p : (96 + p);
            int idx = (km * u) & 127;
            float2 cs = tcs[idx];
            ax += op[p].x * cs.x - op[p].y * cs.y;  // a * e^{+i th}
            ay += op[p].x * cs.y + op[p].y * cs.x;
        }
        T[((size_t)(b * 128 + u) * 16 + q) * 64 + o] = make_float2(ax, ay);
    }
}

// k56 v2: all-MFMA fused tail. One block per bm=(b,u), 4 waves, wave owns 32 rows
// end-to-end (y -> h -> out). ONE __syncthreads per block (after table staging).
//   y = relu(x@wl + bl + Ctb@Tpk)   [residual MFMA + spectral-assembly MFMA]
//   per head: h = relu(y@W1+b1); out = h@W2+b2   [weights straight from L2]
// LDS 52 KB -> 3 blocks/CU. All tiles chunk(16B)-XOR swizzled for free b128 reads.
__global__ __launch_bounds__(256, 3) void k56_fused(
    const float* __restrict__ x, const float2* __restrict__ T,
    const float* __restrict__ bl,
    const unsigned short* __restrict__ ctb_pre, const unsigned short* __restrict__ wlt_pre,
    const unsigned short* __restrict__ w1bt, const unsigned short* __restrict__ w2bt,
    const float* __restrict__ bb1, const float* __restrict__ bb2,
    const float* __restrict__ bf1, const float* __restrict__ bf2,
    float* __restrict__ out)
{
    __shared__ __align__(16) unsigned short Ctb[4096];   // [v:128][k:32]  8K
    __shared__ __align__(16) unsigned short wlt[4096];   // [o:64][k:64]   8K
    __shared__ __align__(16) unsigned short Tpk[2048];   // [o:64][k:32]   4K
    __shared__ __align__(16) unsigned short ys[8192];    // [v:128][o:64] 16K
    __shared__ __align__(16) unsigned short hs[8192];    // 4 waves x [16][128] 16K

    const int t = threadIdx.x;
    const int bm = blockIdx.x;
    const int lane = t & 63, wv = t >> 6;
    const int ar = lane & 15, kg = lane >> 4;
    const int R0 = wv * 32;

    // ---- stage tables (pre-swizzled: straight copies) + build Tpk ----
    {
        const uint4* cg = (const uint4*)ctb_pre;
        uint4* cl = (uint4*)Ctb;
        for (int k = t; k < 512; k += 256) cl[k] = cg[k];
        const uint4* wg = (const uint4*)wlt_pre;
        uint4* wl4 = (uint4*)wlt;
        for (int k = t; k < 512; k += 256) wl4[k] = wg[k];
        const float2* Tg = T + (size_t)bm * 1024;
        for (int idx = t; idx < 1024; idx += 256) {
            int q = idx >> 6, o = idx & 63;
            float2 v = Tg[idx];
            int f = (o >> 1) & 3;
            Tpk[o * 32 + (((q >> 3) ^ f) << 3) + (q & 7)] = f2bf(v.x);
            Tpk[o * 32 + (((2 + (q >> 3)) ^ f) << 3) + (q & 7)] = f2bf(v.y);
        }
    }
    __syncthreads();   // the only block-wide barrier

    // bias preloads (L1/L2-hot scalars)
    float biasl[4];
    #pragma unroll
    for (int ct = 0; ct < 4; ++ct) biasl[ct] = bl[ct * 16 + ar];

    // ---- phase A: y rows R0..R0+31 via MFMA ----
    #pragma unroll
    for (int rt = 0; rt < 2; ++rt) {
        const int vrow = R0 + rt * 16 + ar;
        const float* xr = x + (size_t)bm * 8192 + vrow * 64 + kg * 8;
        float4 xa0 = *(const float4*)(xr);
        float4 xa1 = *(const float4*)(xr + 4);
        float4 xb0 = *(const float4*)(xr + 32);
        float4 xb1 = *(const float4*)(xr + 36);
        bf16x8 a0 = cvt8(xa0, xa1);
        bf16x8 a1 = cvt8(xb0, xb1);
        bf16x8 asp = *(const bf16x8*)&Ctb[vrow * 32 + ((kg ^ ((vrow >> 1) & 3)) << 3)];
        f32x4 acc[4];
        #pragma unroll
        for (int ct = 0; ct < 4; ++ct) acc[ct] = (f32x4){0.f, 0.f, 0.f, 0.f};
        #pragma unroll
        for (int ct = 0; ct < 4; ++ct) {
            int o = ct * 16 + ar;
            bf16x8 b0 = *(const bf16x8*)&wlt[o * 64 + ((kg ^ (o & 7)) << 3)];
            bf16x8 b1 = *(const bf16x8*)&wlt[o * 64 + (((4 + kg) ^ (o & 7)) << 3)];
            bf16x8 bsp = *(const bf16x8*)&Tpk[o * 32 + ((kg ^ ((o >> 1) & 3)) << 3)];
            acc[ct] = __builtin_amdgcn_mfma_f32_16x16x32_bf16(a0, b0, acc[ct], 0, 0, 0);
            acc[ct] = __builtin_amdgcn_mfma_f32_16x16x32_bf16(a1, b1, acc[ct], 0, 0, 0);
            acc[ct] = __builtin_amdgcn_mfma_f32_16x16x32_bf16(asp, bsp, acc[ct], 0, 0, 0);
        }
        #pragma unroll
        for (int ct = 0; ct < 4; ++ct) {
            int col = ct * 16 + ar;
            #pragma unroll
            for (int r = 0; r < 4; ++r) {
                int row = R0 + rt * 16 + kg * 4 + r;
                float v = fmaxf(acc[ct][r] + biasl[ct], 0.f);
                ys[row * 64 + (((col >> 3) ^ (row & 7)) << 3) + (col & 7)] = f2bf(v);
            }
        }
    }
    // no barrier: ys rows are wave-private; compiler orders LDS within the wave

    // ---- phase B: heads, wave-local ----
    unsigned short* hw = hs + wv * 2048;   // [16][128] wave-private
    #pragma unroll
    for (int head = 0; head < 2; ++head) {
        const unsigned short* W1 = w1bt + head * 8192;
        const unsigned short* W2 = w2bt + head * 8192;
        const float* B1 = head ? bf1 : bb1;
        const float* B2 = head ? bf2 : bb2;
        float bias1[8], bias2[4];
        #pragma unroll
        for (int c = 0; c < 8; ++c) bias1[c] = B1[c * 16 + ar];
        #pragma unroll
        for (int c = 0; c < 4; ++c) bias2[c] = B2[c * 16 + ar];

        #pragma unroll
        for (int rt = 0; rt < 2; ++rt) {
            const int rowbase = R0 + rt * 16;
            // GEMM1: 16 x 128, K=64. A from ys (LDS), B from global (L2-hot).
            const int yrow = rowbase + ar;
            bf16x8 ya0 = *(const bf16x8*)&ys[yrow * 64 + ((kg ^ (ar & 7)) << 3)];
            bf16x8 ya1 = *(const bf16x8*)&ys[yrow * 64 + (((4 + kg) ^ (ar & 7)) << 3)];
            f32x4 acc1[8];
            #pragma unroll
            for (int ct = 0; ct < 8; ++ct) acc1[ct] = (f32x4){0.f, 0.f, 0.f, 0.f};
            #pragma unroll
            for (int ct = 0; ct < 8; ++ct) {
                const unsigned short* wp = W1 + (ct * 16 + ar) * 64 + kg * 8;
                bf16x8 b0 = *(const bf16x8*)(wp);
                bf16x8 b1 = *(const bf16x8*)(wp + 32);
                acc1[ct] = __builtin_amdgcn_mfma_f32_16x16x32_bf16(ya0, b0, acc1[ct], 0, 0, 0);
                acc1[ct] = __builtin_amdgcn_mfma_f32_16x16x32_bf16(ya1, b1, acc1[ct], 0, 0, 0);
            }
            // h -> wave-private LDS (swizzled), relu+bias
            #pragma unroll
            for (int ct = 0; ct < 8; ++ct) {
                #pragma unroll
                for (int r = 0; r < 4; ++r) {
                    int row = kg * 4 + r;          // 0..15 local
                    int col = ct * 16 + ar;
                    float v = fmaxf(acc1[ct][r] + bias1[ct], 0.f);
                    hw[row * 128 + (((col >> 3) ^ (row & 7)) << 3) + (col & 7)] = f2bf(v);
                }
            }
            // GEMM2: 16 x 64, K=128. A from hw (LDS), B from global.
            f32x4 acc2[4];
            #pragma unroll
            for (int ct = 0; ct < 4; ++ct) acc2[ct] = (f32x4){0.f, 0.f, 0.f, 0.f};
            #pragma unroll
            for (int ks = 0; ks < 4; ++ks) {
                bf16x8 a = *(const bf16x8*)&hw[ar * 128 + (((ks * 4 + kg) ^ (ar & 7)) << 3)];
                #pragma unroll
                for (int ct = 0; ct < 4; ++ct) {
                    const unsigned short* wp = W2 + (ct * 16 + ar) * 128 + ks * 32 + kg * 8;
                    bf16x8 b = *(const bf16x8*)wp;
                    acc2[ct] = __builtin_amdgcn_mfma_f32_16x16x32_bf16(a, b, acc2[ct], 0, 0, 0);
                }
            }
            float* og = out + (size_t)head * 33554432u + (size_t)bm * 8192;
            #pragma unroll
            for (int ct = 0; ct < 4; ++ct) {
                #pragma unroll
                for (int r = 0; r < 4; ++r)
                    og[(size_t)(rowbase + kg * 4 + r) * 64 + ct * 16 + ar] =
                        acc2[ct][r] + bias2[ct];
            }
        }
    }
}

extern "C" void kernel_launch(void* const* d_in, const int* in_sizes, int n_in,
                              void* d_out, int out_size, void* d_ws, size_t ws_size,
                              hipStream_t stream)
{
    (void)in_sizes; (void)n_in; (void)out_size; (void)ws_size;
    const float* x   = (const float*)d_in[0];
    const float* ws0 = (const float*)d_in[1];
    const float* ws1 = (const float*)d_in[2];
    const float* wl  = (const float*)d_in[3];
    const float* bl  = (const float*)d_in[4];
    const float* wb1 = (const float*)d_in[5];
    const float* bb1 = (const float*)d_in[6];
    const float* wb2 = (const float*)d_in[7];
    const float* bb2 = (const float*)d_in[8];
    const float* wf1 = (const float*)d_in[9];
    const float* bf1 = (const float*)d_in[10];
    const float* wf2 = (const float*)d_in[11];
    const float* bf2 = (const float*)d_in[12];
    float* out = (float*)d_out;

    float* ws = (float*)d_ws;
    float2* w0t = (float2*)ws;                     // 131072 float2
    float2* w1t = (float2*)(ws + 262144);          // 131072 float2
    float2* Tb  = (float2*)(ws + 524288);          // 4194304 float2
    float2* Ab  = (float2*)(ws + 8912896);         // 4194304 float2 (dead after k2)
    float2* xft = (float2*)(ws + 17301504);        // 1048576 float2 (dead after k3a)
    float2* c1b = (float2*)(ws + 19398656);        // 1048576 float2 (dead after k3b)
    float2* oft = (float2*)(ws + 21495808);        // 1048576 float2 (dead after k4)
    unsigned short* w1bt    = (unsigned short*)(ws + 23592960);  // 16384 u16
    unsigned short* w2bt    = (unsigned short*)(ws + 23601152);  // 16384 u16
    unsigned short* wlt_pre = (unsigned short*)(ws + 23609344);  // 4096 u16
    unsigned short* ctb_pre = (unsigned short*)(ws + 23611392);  // 4096 u16

    k0_prep    <<<1024, 256, 0, stream>>>(ws0, ws1, w0t, w1t);
    k0b_prep   <<<160,  256, 0, stream>>>(wb1, wf1, wb2, wf2, wl,
                                          w1bt, w2bt, wlt_pre, ctb_pre);
    k1_dft_n   <<<4096, 256, 0, stream>>>(x, Ab);
    k2_dft_m   <<<512,  256, 0, stream>>>(Ab, xft);
    k3a_spec1  <<<1024, 256, 0, stream>>>(xft, w0t, c1b);
    k3b_spec2  <<<1024, 256, 0, stream>>>(c1b, w1t, oft);
    k4_idft_m  <<<512,  256, 0, stream>>>(oft, Tb);
    k56_fused  <<<4096, 256, 0, stream>>>(x, Tb, bl, ctb_pre, wlt_pre,
                                          w1bt, w2bt, bb1, bb2, bf1, bf2, out);
}

// Round 6
// 375.749 us; speedup vs baseline: 1.4731x; 1.4731x over previous
//
#include <hip/hip_runtime.h>
#include <hip/hip_bf16.h>

#define TWO_PI 6.28318530717958647692f

typedef __attribute__((ext_vector_type(8))) short bf16x8;
typedef __attribute__((ext_vector_type(4))) float f32x4;

__device__ __forceinline__ unsigned short f2bf(float v) {
    __hip_bfloat16 h = __float2bfloat16(v);
    return *(unsigned short*)&h;
}

__device__ __forceinline__ bf16x8 cvt8(float4 a, float4 b) {
    bf16x8 r;
    r[0] = (short)f2bf(a.x); r[1] = (short)f2bf(a.y);
    r[2] = (short)f2bf(a.z); r[3] = (short)f2bf(a.w);
    r[4] = (short)f2bf(b.x); r[5] = (short)f2bf(b.y);
    r[6] = (short)f2bf(b.z); r[7] = (short)f2bf(b.w);
    return r;
}

// Problem: B=32, M=N=128, I=O=64, NM=16.
// Spectral path keeps only km in {0..15, 112..127} (p=0..31) and kn=0..15 (q).
// T (spectral pre-irfft) ~2e-5 magnitude -> bf16 there is free.
//
// R5 lesson: MFMA B-operands MUST come from LDS/registers. Global (L2) operand
// loads in the inner loop serialize at ~200cyc each -> both pipes idle.
//
// ws layout (float offsets):
//   w0t     @ 0        : 262144   (32 p x 64 i x 64 j complex)
//   w1t     @ 262144   : 262144   (2 h x 16 kv x 64 j x 64 o complex)
//   T       @ 524288   : 8388608  ([b][u][q][o] complex)
//   A       @ 8912896  : 8388608  ([b][m][kv][i] complex)  (dead after k2)
//   xft     @ 17301504 : 2097152  (dead after k3a)
//   c1      @ 19398656 : 2097152  (dead after k3b)
//   oft     @ 21495808 : 2097152  (dead after k4)
//   w1bt    @ 23592960 : 16384 u16  W1t[2][o:128][k:64] bf16
//   w2bt    @ 23601152 : 16384 u16  W2t[2][o:64][k:128] bf16
//   wlt_pre @ 23609344 : 4096 u16   w_lin^T [o:64][k:64] bf16, chunk-XOR-swizzled
//   ctb_pre @ 23611392 : 4096 u16   irfft coeff [v:128][k:32] bf16, swizzled

__global__ __launch_bounds__(256) void k0_prep(const float* __restrict__ ws0,
                                               const float* __restrict__ ws1,
                                               float2* __restrict__ w0t,
                                               float2* __restrict__ w1t)
{
    int tgt = blockIdx.x * 256 + threadIdx.x;   // 0..262143
    if (tgt < 131072) {
        int p = tgt >> 12;
        int rem = tgt & 4095;
        int i = rem >> 6, j = rem & 63;
        const float* s = (p < 16) ? ws0 : ws1;   // f=0 plane
        int px = p & 15;
        int base = ((i * 64 + j) * 16 + px) * 2;
        w0t[tgt] = make_float2(s[base], s[base + 1]);
    } else {
        int u = tgt - 131072;
        int h = u >> 16;
        int kv = (u >> 12) & 15;
        int j = (u >> 6) & 63;
        int o = u & 63;
        const float* s = (h ? ws1 : ws0) + 131072;  // f=1 plane
        int base = ((j * 64 + o) * 16 + kv) * 2;
        w1t[u] = make_float2(s[base], s[base + 1]);
    }
}

// head weights bf16-transposed + w_lin^T + irfft coefficient matrix
__global__ __launch_bounds__(256) void k0b_prep(const float* __restrict__ wb1,
                                                const float* __restrict__ wf1,
                                                const float* __restrict__ wb2,
                                                const float* __restrict__ wf2,
                                                const float* __restrict__ wl,
                                                unsigned short* __restrict__ w1bt,
                                                unsigned short* __restrict__ w2bt,
                                                unsigned short* __restrict__ wlt_pre,
                                                unsigned short* __restrict__ ctb_pre)
{
    int tgt = blockIdx.x * 256 + threadIdx.x;   // 0..40959
    if (tgt < 16384) {
        int head = tgt >> 13;
        int o = (tgt >> 6) & 127;
        int i = tgt & 63;
        const float* src = head ? wf1 : wb1;    // [64][128]
        w1bt[tgt] = f2bf(src[i * 128 + o]);
    } else if (tgt < 32768) {
        int u = tgt - 16384;
        int head = u >> 13;
        int o = (u >> 7) & 63;
        int c = u & 127;
        const float* src = head ? wf2 : wb2;    // [128][64]
        w2bt[u] = f2bf(src[c * 64 + o]);
    } else if (tgt < 36864) {
        int u = tgt - 32768;                    // 0..4095
        int o = u >> 6, i = u & 63;
        int chunk = (i >> 3) ^ (o & 7);
        wlt_pre[o * 64 + chunk * 8 + (i & 7)] = f2bf(wl[i * 64 + o]);
    } else {
        int u = tgt - 36864;                    // 0..4095
        int v = u >> 5, k = u & 31;             // v 0..127, k 0..31
        float val;
        if (k < 16) {
            val = (k == 0) ? (1.0f / 128.0f)
                           : (2.0f / 128.0f) * cosf(TWO_PI * k * v * (1.0f / 128.0f));
        } else {
            int q = k - 16;
            val = (q == 0) ? 0.f
                           : -(2.0f / 128.0f) * sinf(TWO_PI * q * v * (1.0f / 128.0f));
        }
        int chunk = (k >> 3) ^ ((v >> 1) & 3);
        ctb_pre[v * 32 + chunk * 8 + (k & 7)] = f2bf(val);
    }
}

// k1: A[b,m,kv,i] = sum_n x[b,m,n,i] * exp(-2pi i kv n/128), kv=0..15
__global__ __launch_bounds__(256) void k1_dft_n(const float* __restrict__ x,
                                                float2* __restrict__ A)
{
    __shared__ float Xs[128][64];
    __shared__ __align__(8) float2 tcs[128];
    const int t = threadIdx.x;
    const int bm = blockIdx.x;
    if (t < 128) { float a = t * (TWO_PI / 128.0f); tcs[t] = make_float2(cosf(a), sinf(a)); }
    const float4* xg4 = (const float4*)(x + (size_t)bm * 8192);
    float4* Xs4 = (float4*)&Xs[0][0];
    for (int k = t; k < 2048; k += 256) Xs4[k] = xg4[k];
    __syncthreads();
    const int i = t & 63;
    const int kv0 = (t >> 6) << 2;
    float re[4] = {0.f, 0.f, 0.f, 0.f}, im[4] = {0.f, 0.f, 0.f, 0.f};
    for (int n = 0; n < 128; ++n) {
        float v = Xs[n][i];
        #pragma unroll
        for (int j = 0; j < 4; ++j) {
            int idx = ((kv0 + j) * n) & 127;
            float2 w = tcs[idx];
            re[j] += v * w.x;
            im[j] -= v * w.y;
        }
    }
    float2* Ap = A + (size_t)bm * 1024;
    #pragma unroll
    for (int j = 0; j < 4; ++j) Ap[(kv0 + j) * 64 + i] = make_float2(re[j], im[j]);
}

// k2: xft[b,p,kv,i] = (1/128) sum_m A[b,m,kv,i] * exp(-2pi i km(p) m/128)
__global__ __launch_bounds__(256) void k2_dft_m(const float2* __restrict__ A,
                                                float2* __restrict__ xft)
{
    __shared__ float2 As[128][64];
    __shared__ __align__(8) float2 tcs[128];
    const int t = threadIdx.x;
    const int b = blockIdx.x >> 4, kv = blockIdx.x & 15;
    if (t < 128) { float a = t * (TWO_PI / 128.0f); tcs[t] = make_float2(cosf(a), sinf(a)); }
    for (int k = t; k < 8192; k += 256) {
        int m = k >> 6, i = k & 63;
        As[m][i] = A[((size_t)(b * 128 + m) * 16 + kv) * 64 + i];
    }
    __syncthreads();
    const int i = t & 63;
    const int p0 = (t >> 6) << 3;
    float2 acc[8];
    #pragma unroll
    for (int j = 0; j < 8; ++j) acc[j] = make_float2(0.f, 0.f);
    for (int m = 0; m < 128; ++m) {
        float2 a = As[m][i];
        #pragma unroll
        for (int j = 0; j < 8; ++j) {
            int p = p0 + j;
            int km = (p < 16) ? p : (96 + p);     // p>=16 -> km = 112 + (p-16)
            int idx = (km * m) & 127;
            float2 cs = tcs[idx];
            acc[j].x += a.x * cs.x + a.y * cs.y;  // a * e^{-i th}
            acc[j].y += a.y * cs.x - a.x * cs.y;
        }
    }
    const float sc = 1.0f / 128.0f;
    #pragma unroll
    for (int j = 0; j < 8; ++j)
        xft[((size_t)(b * 32 + p0 + j) * 16 + kv) * 64 + i] =
            make_float2(acc[j].x * sc, acc[j].y * sc);
}

// k3a: c1[b,p,kv,j] = sum_i xft[b,p,kv,i] * w0c[i,j,p]
__global__ __launch_bounds__(256) void k3a_spec1(const float2* __restrict__ xft,
                                                 const float2* __restrict__ w0t,
                                                 float2* __restrict__ c1)
{
    __shared__ __align__(16) float2 xs[16][64];
    __shared__ __align__(16) float2 w0s[64][64];
    const int t = threadIdx.x;
    const int b = blockIdx.x >> 5, p = blockIdx.x & 31;
    const float2* xg = xft + (size_t)(b * 32 + p) * 1024;
    for (int k = t; k < 1024; k += 256) ((float2*)xs)[k] = xg[k];
    const float4* wg = (const float4*)(w0t + (size_t)p * 4096);
    for (int k = t; k < 2048; k += 256) ((float4*)w0s)[k] = wg[k];
    __syncthreads();
    const int j = t & 63;
    const int kv0 = (t >> 6) << 2;
    float2 acc[4];
    #pragma unroll
    for (int q = 0; q < 4; ++q) acc[q] = make_float2(0.f, 0.f);
    for (int i = 0; i < 64; ++i) {
        float2 w = w0s[i][j];
        #pragma unroll
        for (int q = 0; q < 4; ++q) {
            float2 a = xs[kv0 + q][i];
            acc[q].x += a.x * w.x - a.y * w.y;
            acc[q].y += a.x * w.y + a.y * w.x;
        }
    }
    #pragma unroll
    for (int q = 0; q < 4; ++q)
        c1[((size_t)(b * 32 + p) * 16 + kv0 + q) * 64 + j] = acc[q];
}

// k3b: oft[b,p,kv,o] = sum_j c1[b,p,kv,j] * w1c[j,o,kv]  (weights per half h=p/16)
__global__ __launch_bounds__(256) void k3b_spec2(const float2* __restrict__ c1,
                                                 const float2* __restrict__ w1t,
                                                 float2* __restrict__ oft)
{
    __shared__ __align__(16) float2 cs[16][64];
    __shared__ __align__(16) float2 w1s[64][64];
    const int t = threadIdx.x;
    int id = blockIdx.x;
    const int h = id & 1; id >>= 1;
    const int kv = id & 15; const int b = id >> 4;
    for (int k = t; k < 1024; k += 256) {
        int pp = k >> 6, j = k & 63;
        cs[pp][j] = c1[((size_t)(b * 32 + h * 16 + pp) * 16 + kv) * 64 + j];
    }
    const float4* wg = (const float4*)(w1t + (size_t)(h * 16 + kv) * 4096);
    for (int k = t; k < 2048; k += 256) ((float4*)w1s)[k] = wg[k];
    __syncthreads();
    const int o = t & 63;
    const int pp0 = (t >> 6) << 2;
    float2 acc[4];
    #pragma unroll
    for (int q = 0; q < 4; ++q) acc[q] = make_float2(0.f, 0.f);
    for (int j = 0; j < 64; ++j) {
        float2 w = w1s[j][o];
        #pragma unroll
        for (int q = 0; q < 4; ++q) {
            float2 a = cs[pp0 + q][j];
            acc[q].x += a.x * w.x - a.y * w.y;
            acc[q].y += a.x * w.y + a.y * w.x;
        }
    }
    #pragma unroll
    for (int q = 0; q < 4; ++q)
        oft[((size_t)(b * 32 + h * 16 + pp0 + q) * 16 + kv) * 64 + o] = acc[q];
}

// k4: T[b,u,q,o] = sum_p oft[b,p,q,o] * exp(+2pi i km(p) u/128)
__global__ __launch_bounds__(256) void k4_idft_m(const float2* __restrict__ oft,
                                                 float2* __restrict__ T)
{
    __shared__ float2 Os[32][64];
    __shared__ __align__(8) float2 tcs[128];
    const int t = threadIdx.x;
    const int b = blockIdx.x >> 4, q = blockIdx.x & 15;
    if (t < 128) { float a = t * (TWO_PI / 128.0f); tcs[t] = make_float2(cosf(a), sinf(a)); }
    for (int k = t; k < 2048; k += 256) {
        int p = k >> 6, o = k & 63;
        Os[p][o] = oft[((size_t)(b * 32 + p) * 16 + q) * 64 + o];
    }
    __syncthreads();
    const int o = t & 63;
    const int u0 = (t >> 6) << 5;
    float2 op[32];
    #pragma unroll
    for (int p = 0; p < 32; ++p) op[p] = Os[p][o];
    for (int du = 0; du < 32; ++du) {
        int u = u0 + du;
        float ax = 0.f, ay = 0.f;
        #pragma unroll
        for (int p = 0; p < 32; ++p) {
            int km = (p < 16) ? p : (96 + p);
            int idx = (km * u) & 127;
            float2 cs = tcs[idx];
            ax += op[p].x * cs.x - op[p].y * cs.y;  // a * e^{+i th}
            ay += op[p].x * cs.y + op[p].y * cs.x;
        }
        T[((size_t)(b * 128 + u) * 16 + q) * 64 + o] = make_float2(ax, ay);
    }
}

// k56 v3: all-MFMA fused tail, LDS-staged weights (R5 fix).
// One block per bm=(b,u), 4 waves, wave owns 32 rows end-to-end.
// LDS 68 KB -> 2 blocks/CU. 5 barriers/block. Region RA (20K) holds phase-A
// tables, then is reused for w2s (weights staged per head).
__global__ __launch_bounds__(256) void k56_fused(
    const float* __restrict__ x, const float2* __restrict__ T,
    const float* __restrict__ bl,
    const unsigned short* __restrict__ ctb_pre, const unsigned short* __restrict__ wlt_pre,
    const unsigned short* __restrict__ w1bt, const unsigned short* __restrict__ w2bt,
    const float* __restrict__ bb1, const float* __restrict__ bb2,
    const float* __restrict__ bf1, const float* __restrict__ bf2,
    float* __restrict__ out)
{
    __shared__ __align__(16) unsigned char RA[20480];    // Ctb 8K | wlt 8K | Tpk 4K -> w2s 16K
    __shared__ __align__(16) unsigned short w1s[8192];   // [o:128][k:64] swizzled, 16K
    __shared__ __align__(16) unsigned short ys[8192];    // [v:128][o:64] swizzled, 16K
    __shared__ __align__(16) unsigned short hs[8192];    // 4 waves x [16][128] swizzled, 16K

    unsigned short* Ctb = (unsigned short*)RA;           // [v:128][k:32]
    unsigned short* wlt = (unsigned short*)(RA + 8192);  // [o:64][k:64]
    unsigned short* Tpk = (unsigned short*)(RA + 16384); // [o:64][k:32]
    unsigned short* w2s = (unsigned short*)RA;           // [o:64][k:128]

    const int t = threadIdx.x;
    const int bm = blockIdx.x;
    const int lane = t & 63, wv = t >> 6;
    const int ar = lane & 15, kg = lane >> 4;
    const int R0 = wv * 32;

    // ---- B1 stage: tables (pre-swizzled straight copies), w1s(head0), Tpk ----
    {
        const uint4* cg = (const uint4*)ctb_pre;
        for (int k = t; k < 512; k += 256) ((uint4*)Ctb)[k] = cg[k];
        const uint4* wg = (const uint4*)wlt_pre;
        for (int k = t; k < 512; k += 256) ((uint4*)wlt)[k] = wg[k];
        const uint4* g1 = (const uint4*)w1bt;
        for (int k = t; k < 1024; k += 256) {
            int row = k >> 3, ch = k & 7;
            *(uint4*)&w1s[row * 64 + ((ch ^ (row & 7)) << 3)] = g1[k];
        }
        const float2* Tg = T + (size_t)bm * 1024;
        for (int idx = t; idx < 1024; idx += 256) {
            int q = idx >> 6, o = idx & 63;
            float2 v = Tg[idx];
            int f = (o >> 1) & 3;
            Tpk[o * 32 + (((q >> 3) ^ f) << 3) + (q & 7)] = f2bf(v.x);
            Tpk[o * 32 + (((2 + (q >> 3)) ^ f) << 3) + (q & 7)] = f2bf(v.y);
        }
    }
    __syncthreads();

    float biasl[4];
    #pragma unroll
    for (int ct = 0; ct < 4; ++ct) biasl[ct] = bl[ct * 16 + ar];

    // ---- phase A: y rows R0..R0+31 via MFMA (residual + spectral assembly) ----
    #pragma unroll
    for (int rt = 0; rt < 2; ++rt) {
        const int vrow = R0 + rt * 16 + ar;
        const float* xr = x + (size_t)bm * 8192 + vrow * 64 + kg * 8;
        float4 xa0 = *(const float4*)(xr);
        float4 xa1 = *(const float4*)(xr + 4);
        float4 xb0 = *(const float4*)(xr + 32);
        float4 xb1 = *(const float4*)(xr + 36);
        bf16x8 a0 = cvt8(xa0, xa1);
        bf16x8 a1 = cvt8(xb0, xb1);
        bf16x8 asp = *(const bf16x8*)&Ctb[vrow * 32 + ((kg ^ ((vrow >> 1) & 3)) << 3)];
        f32x4 acc[4];
        #pragma unroll
        for (int ct = 0; ct < 4; ++ct) acc[ct] = (f32x4){0.f, 0.f, 0.f, 0.f};
        #pragma unroll
        for (int ct = 0; ct < 4; ++ct) {
            int o = ct * 16 + ar;
            bf16x8 b0 = *(const bf16x8*)&wlt[o * 64 + ((kg ^ (o & 7)) << 3)];
            bf16x8 b1 = *(const bf16x8*)&wlt[o * 64 + (((4 + kg) ^ (o & 7)) << 3)];
            bf16x8 bsp = *(const bf16x8*)&Tpk[o * 32 + ((kg ^ ((o >> 1) & 3)) << 3)];
            acc[ct] = __builtin_amdgcn_mfma_f32_16x16x32_bf16(a0, b0, acc[ct], 0, 0, 0);
            acc[ct] = __builtin_amdgcn_mfma_f32_16x16x32_bf16(a1, b1, acc[ct], 0, 0, 0);
            acc[ct] = __builtin_amdgcn_mfma_f32_16x16x32_bf16(asp, bsp, acc[ct], 0, 0, 0);
        }
        #pragma unroll
        for (int ct = 0; ct < 4; ++ct) {
            int col = ct * 16 + ar;
            #pragma unroll
            for (int r = 0; r < 4; ++r) {
                int row = R0 + rt * 16 + kg * 4 + r;
                float v = fmaxf(acc[ct][r] + biasl[ct], 0.f);
                ys[row * 64 + (((col >> 3) ^ (row & 7)) << 3) + (col & 7)] = f2bf(v);
            }
        }
    }
    __syncthreads();   // B2: phase-A table reads done -> RA reusable

    // ---- phase B: heads; weights staged in LDS ----
    unsigned short* hw = hs + wv * 2048;   // [16][128] wave-private
    for (int head = 0; head < 2; ++head) {
        if (head) {
            const uint4* g1 = (const uint4*)(w1bt + 8192);
            for (int k = t; k < 1024; k += 256) {
                int row = k >> 3, ch = k & 7;
                *(uint4*)&w1s[row * 64 + ((ch ^ (row & 7)) << 3)] = g1[k];
            }
        }
        {
            const uint4* g2 = (const uint4*)(w2bt + head * 8192);
            for (int k = t; k < 1024; k += 256) {
                int row = k >> 4, ch = k & 15;
                *(uint4*)&w2s[row * 128 + ((ch ^ (row & 7)) << 3)] = g2[k];
            }
        }
        const float* B1 = head ? bf1 : bb1;
        const float* B2 = head ? bf2 : bb2;
        float bias1[8], bias2[4];
        #pragma unroll
        for (int c = 0; c < 8; ++c) bias1[c] = B1[c * 16 + ar];
        #pragma unroll
        for (int c = 0; c < 4; ++c) bias2[c] = B2[c * 16 + ar];
        __syncthreads();   // B3/B5: weights visible

        #pragma unroll
        for (int rt = 0; rt < 2; ++rt) {
            const int rowbase = R0 + rt * 16;
            // GEMM1: 16 x 128, K=64. A from ys, B from w1s (both LDS).
            const int yrow = rowbase + ar;
            bf16x8 ya0 = *(const bf16x8*)&ys[yrow * 64 + ((kg ^ (ar & 7)) << 3)];
            bf16x8 ya1 = *(const bf16x8*)&ys[yrow * 64 + (((4 + kg) ^ (ar & 7)) << 3)];
            f32x4 acc1[8];
            #pragma unroll
            for (int ct = 0; ct < 8; ++ct) acc1[ct] = (f32x4){0.f, 0.f, 0.f, 0.f};
            #pragma unroll
            for (int ct = 0; ct < 8; ++ct) {
                int brow = ct * 16 + ar;
                bf16x8 b0 = *(const bf16x8*)&w1s[brow * 64 + ((kg ^ (ar & 7)) << 3)];
                bf16x8 b1 = *(const bf16x8*)&w1s[brow * 64 + (((4 + kg) ^ (ar & 7)) << 3)];
                acc1[ct] = __builtin_amdgcn_mfma_f32_16x16x32_bf16(ya0, b0, acc1[ct], 0, 0, 0);
                acc1[ct] = __builtin_amdgcn_mfma_f32_16x16x32_bf16(ya1, b1, acc1[ct], 0, 0, 0);
            }
            // h -> wave-private LDS (swizzled), relu+bias
            #pragma unroll
            for (int ct = 0; ct < 8; ++ct) {
                #pragma unroll
                for (int r = 0; r < 4; ++r) {
                    int row = kg * 4 + r;          // 0..15 local
                    int col = ct * 16 + ar;
                    float v = fmaxf(acc1[ct][r] + bias1[ct], 0.f);
                    hw[row * 128 + (((col >> 3) ^ (row & 7)) << 3) + (col & 7)] = f2bf(v);
                }
            }
            // GEMM2: 16 x 64, K=128. A from hw, B from w2s (both LDS).
            f32x4 acc2[4];
            #pragma unroll
            for (int ct = 0; ct < 4; ++ct) acc2[ct] = (f32x4){0.f, 0.f, 0.f, 0.f};
            #pragma unroll
            for (int ks = 0; ks < 4; ++ks) {
                bf16x8 a = *(const bf16x8*)&hw[ar * 128 + (((ks * 4 + kg) ^ (ar & 7)) << 3)];
                #pragma unroll
                for (int ct = 0; ct < 4; ++ct) {
                    int brow = ct * 16 + ar;
                    bf16x8 b = *(const bf16x8*)&w2s[brow * 128 + (((ks * 4 + kg) ^ (ar & 7)) << 3)];
                    acc2[ct] = __builtin_amdgcn_mfma_f32_16x16x32_bf16(a, b, acc2[ct], 0, 0, 0);
                }
            }
            float* og = out + (size_t)head * 33554432u + (size_t)bm * 8192;
            #pragma unroll
            for (int ct = 0; ct < 4; ++ct) {
                #pragma unroll
                for (int r = 0; r < 4; ++r)
                    og[(size_t)(rowbase + kg * 4 + r) * 64 + ct * 16 + ar] =
                        acc2[ct][r] + bias2[ct];
            }
        }
        if (head == 0) __syncthreads();   // B4: weight reads done before restage
    }
}

extern "C" void kernel_launch(void* const* d_in, const int* in_sizes, int n_in,
                              void* d_out, int out_size, void* d_ws, size_t ws_size,
                              hipStream_t stream)
{
    (void)in_sizes; (void)n_in; (void)out_size; (void)ws_size;
    const float* x   = (const float*)d_in[0];
    const float* ws0 = (const float*)d_in[1];
    const float* ws1 = (const float*)d_in[2];
    const float* wl  = (const float*)d_in[3];
    const float* bl  = (const float*)d_in[4];
    const float* wb1 = (const float*)d_in[5];
    const float* bb1 = (const float*)d_in[6];
    const float* wb2 = (const float*)d_in[7];
    const float* bb2 = (const float*)d_in[8];
    const float* wf1 = (const float*)d_in[9];
    const float* bf1 = (const float*)d_in[10];
    const float* wf2 = (const float*)d_in[11];
    const float* bf2 = (const float*)d_in[12];
    float* out = (float*)d_out;

    float* ws = (float*)d_ws;
    float2* w0t = (float2*)ws;                     // 131072 float2
    float2* w1t = (float2*)(ws + 262144);          // 131072 float2
    float2* Tb  = (float2*)(ws + 524288);          // 4194304 float2
    float2* Ab  = (float2*)(ws + 8912896);         // 4194304 float2 (dead after k2)
    float2* xft = (float2*)(ws + 17301504);        // 1048576 float2 (dead after k3a)
    float2* c1b = (float2*)(ws + 19398656);        // 1048576 float2 (dead after k3b)
    float2* oft = (float2*)(ws + 21495808);        // 1048576 float2 (dead after k4)
    unsigned short* w1bt    = (unsigned short*)(ws + 23592960);  // 16384 u16
    unsigned short* w2bt    = (unsigned short*)(ws + 23601152);  // 16384 u16
    unsigned short* wlt_pre = (unsigned short*)(ws + 23609344);  // 4096 u16
    unsigned short* ctb_pre = (unsigned short*)(ws + 23611392);  // 4096 u16

    k0_prep    <<<1024, 256, 0, stream>>>(ws0, ws1, w0t, w1t);
    k0b_prep   <<<160,  256, 0, stream>>>(wb1, wf1, wb2, wf2, wl,
                                          w1bt, w2bt, wlt_pre, ctb_pre);
    k1_dft_n   <<<4096, 256, 0, stream>>>(x, Ab);
    k2_dft_m   <<<512,  256, 0, stream>>>(Ab, xft);
    k3a_spec1  <<<1024, 256, 0, stream>>>(xft, w0t, c1b);
    k3b_spec2  <<<1024, 256, 0, stream>>>(c1b, w1t, oft);
    k4_idft_m  <<<512,  256, 0, stream>>>(oft, Tb);
    k56_fused  <<<4096, 256, 0, stream>>>(x, Tb, bl, ctb_pre, wlt_pre,
                                          w1bt, w2bt, bb1, bb2, bf1, bf2, out);
}